// Round 19
// baseline (773.645 us; speedup 1.0000x reference)
//
#include <hip/hip_runtime.h>
#include <hip/hip_bf16.h>

typedef __attribute__((ext_vector_type(8))) short bf16x8;
typedef __attribute__((ext_vector_type(4))) float f32x4;

constexpr int BT   = 1024;  // threads/block (16 waves, 1 block/CU)
constexpr int KD   = 96;    // feature/hidden dim
constexpr int LDX  = 104;   // xs row stride in bf16 (208 B, 16B-aligned)
constexpr int LDT  = 12;    // tinv stride in floats (48 B)
constexpr int NBLK = 256;   // persistent blocks (1 per CU)

// d_ws layout: [gbf: 48000 bf16 = 96000 B][cnt: uint @ 96000 (128B-aligned)]
constexpr size_t CNT_OFF = 96000;

__device__ inline ushort f2bf(float f) {  // fp32 -> bf16 RNE
    uint u = __float_as_uint(f);
    u += 0x7fffu + ((u >> 16) & 1u);
    return (ushort)(u >> 16);
}

__device__ inline uint f2bf2(float lo, float hi) {  // packed cvt
    float2 t; t.x = lo; t.y = hi;
    __hip_bfloat162 h = __float22bfloat162_rn(t);
    union { __hip_bfloat162 b; uint u; } cv;
    cv.b = h;
    return cv.u;
}

// prep: geoms f32 -> bf16 table in d_ws; also zero the work-queue counter
__global__ void prep_geoms(const float* __restrict__ g, ushort* __restrict__ gb,
                           uint* __restrict__ cnt, int n) {
    int i = blockIdx.x * 256 + threadIdx.x;
    if (i == 0) cnt[0] = 0u;
    if (i < n) gb[i] = f2bf(g[i]);
}

// f64 adjugate 4x4 inverse; writes rows 0..2 (3x4 floats) to ti
__device__ inline void inv4x4(float4 t0, float4 t1, float4 t2, float4 t3,
                              float* __restrict__ ti) {
    double m00=t0.x, m01=t0.y, m02=t0.z, m03=t0.w;
    double m10=t1.x, m11=t1.y, m12=t1.z, m13=t1.w;
    double m20=t2.x, m21=t2.y, m22=t2.z, m23=t2.w;
    double m30=t3.x, m31=t3.y, m32=t3.z, m33=t3.w;
    double A2323 = m22*m33 - m23*m32;
    double A1323 = m21*m33 - m23*m31;
    double A1223 = m21*m32 - m22*m31;
    double A0323 = m20*m33 - m23*m30;
    double A0223 = m20*m32 - m22*m30;
    double A0123 = m20*m31 - m21*m30;
    double A2313 = m12*m33 - m13*m32;
    double A1313 = m11*m33 - m13*m31;
    double A1213 = m11*m32 - m12*m31;
    double A2312 = m12*m23 - m13*m22;
    double A1312 = m11*m23 - m13*m21;
    double A1212 = m11*m22 - m12*m21;
    double A0313 = m10*m33 - m13*m30;
    double A0213 = m10*m32 - m12*m30;
    double A0312 = m10*m23 - m13*m20;
    double A0212 = m10*m22 - m12*m20;
    double A0113 = m10*m31 - m11*m30;
    double A0112 = m10*m21 - m11*m20;
    double det = m00*(m11*A2323 - m12*A1323 + m13*A1223)
               - m01*(m10*A2323 - m12*A0323 + m13*A0223)
               + m02*(m10*A1323 - m11*A0323 + m13*A0123)
               - m03*(m10*A1223 - m11*A0223 + m12*A0123);
    double idet = 1.0 / det;
    ti[0]  = (float)( idet *  (m11*A2323 - m12*A1323 + m13*A1223) );
    ti[1]  = (float)( idet * -(m01*A2323 - m02*A1323 + m03*A1223) );
    ti[2]  = (float)( idet *  (m01*A2313 - m02*A1313 + m03*A1213) );
    ti[3]  = (float)( idet * -(m01*A2312 - m02*A1312 + m03*A1212) );
    ti[4]  = (float)( idet * -(m10*A2323 - m12*A0323 + m13*A0223) );
    ti[5]  = (float)( idet *  (m00*A2323 - m02*A0323 + m03*A0223) );
    ti[6]  = (float)( idet * -(m00*A2313 - m02*A0313 + m03*A0213) );
    ti[7]  = (float)( idet *  (m00*A2312 - m02*A0312 + m03*A0212) );
    ti[8]  = (float)( idet *  (m10*A1323 - m11*A0323 + m13*A0123) );
    ti[9]  = (float)( idet * -(m00*A1323 - m01*A0323 + m03*A0123) );
    ti[10] = (float)( idet *  (m00*A1313 - m01*A0313 + m03*A0113) );
    ti[11] = (float)( idet * -(m00*A1312 - m01*A0312 + m03*A0112) );
}

__global__ void __launch_bounds__(BT, 4) collision_mfma(
    const int* __restrict__ o1, const int* __restrict__ o2,
    const float* __restrict__ Tg, const float* __restrict__ geoms,
    const ushort* __restrict__ gbf, uint* __restrict__ cnt,
    const float* __restrict__ W1, const float* __restrict__ b1,
    const float* __restrict__ W2, const float* __restrict__ b2,
    const float* __restrict__ W3, const float* __restrict__ b3,
    float* __restrict__ out, int N)
{
    __shared__ ushort xs[512 * LDX];      // 16 waves x 32 rows (106496 B)
    __shared__ ushort wlds[36 * 64 * 8];  // frag-major weights (36864 B)
    __shared__ float  tinv[256 * LDT];    // 16 waves x 16 pairs (12288 B)
    __shared__ float  bls[292];           // b1 | b2 | W3 | b3 (1168 B)

    const int tid = threadIdx.x;
    const int w   = tid >> 6;      // wave 0..15
    const int l   = tid & 63;      // lane
    const int cl  = l & 15;        // fragment col within 16-tile
    const int g   = l >> 4;        // k-group 0..3
    const int rg  = g * 4;

    // staging roles (fixed per lane)
    const int rl = l & 31;         // local row 0..31
    const int pt = l >> 5;         // part: elems [pt*24, pt*24+24)
    const int br = rl >> 4;        // branch 0: (x1, T x2)  1: (x2, Tinv x1)
    const int dp = rl & 15;        // local pair 0..15

    // ---- stage weights frag-major + bias/W3, once ----
    for (int e = tid; e < 36 * 512; e += BT) {
        int f    = e >> 9;
        int r    = e & 511;
        int lane = r >> 3;
        int j    = r & 7;
        int L    = f / 18;
        int fr   = f - L * 18;
        int mt   = fr / 3;
        int kb   = fr - mt * 3;
        int gg   = lane >> 4;
        int cc   = lane & 15;
        const float* W = L ? W2 : W1;
        wlds[e] = f2bf(W[(kb * 32 + gg * 8 + j) * KD + mt * 16 + cc]);
    }
    if (tid < 96) {
        bls[tid]       = b1[tid];
        bls[96 + tid]  = b2[tid];
        bls[192 + tid] = W3[tid];
    }
    if (tid == 96) bls[288] = b3[0];
    __syncthreads();   // only runtime barrier; main loop is wave-private

    const int NWT = N >> 4;

    // ===== dynamic work queue: one atomic per wave-tile (kills 16-vs-15 tail) =====
    for (;;) {
        uint tkt = 0;
        if (l == 0) tkt = atomicAdd(cnt, 1u);
        const int wt = (int)__builtin_amdgcn_readfirstlane((int)tkt);
        if (wt >= NWT) break;

        const int pbase = wt * 16;

        // surgical anti-LICM: opaque zero offset, re-made each iteration.
        // wlds/bls reads through wp/bp can't be hoisted (r3/r4/r14 spill guard);
        // everything else schedules freely (no memory clobber).
        uint off0 = 0;
        asm volatile("" : "+v"(off0));
        const ushort* wp = wlds + off0;
        const float*  bp = bls + off0;

        // ===== phase 1: f64 4x4 inverse, lanes 0..15 (wave-private tinv) =====
        if (l < 16) {
            const float4* T4 = reinterpret_cast<const float4*>(Tg + (size_t)(pbase + l) * 16);
            float4 t0 = T4[0], t1 = T4[1], t2 = T4[2], t3 = T4[3];
            inv4x4(t0, t1, t2, t3, &tinv[(w * 16 + l) * LDT]);
        }

        // ===== phase 2: staging, lane = half-row =====
        {
            const int p  = pbase + dp;
            const int ia = o1[p], ib = o2[p];
            const int oa = br ? ib : ia;
            const int ob = br ? ia : ib;
            ushort* xrow = xs + (w * 32 + rl) * LDX;

            // copy half (24 bf16 from pre-converted table)
            {
                const uint4* src = reinterpret_cast<const uint4*>(gbf + oa * 48 + pt * 24);
                uint4* dst = reinterpret_cast<uint4*>(xrow + pt * 24);
                dst[0] = src[0]; dst[1] = src[1]; dst[2] = src[2];
            }

            // transform half: 8 vec3s
            float4 M0, M1, M2;
            if (br == 0) {
                const float4* Tp = reinterpret_cast<const float4*>(Tg + (size_t)p * 16);
                M0 = Tp[0]; M1 = Tp[1]; M2 = Tp[2];
            } else {
                const float4* t4 = reinterpret_cast<const float4*>(&tinv[(w * 16 + dp) * LDT]);
                M0 = t4[0]; M1 = t4[1]; M2 = t4[2];
            }
            float v[24];
            {
                const float4* bs = reinterpret_cast<const float4*>(geoms + (size_t)ob * 48 + pt * 24);
                #pragma unroll
                for (int q = 0; q < 6; ++q) {
                    float4 t = bs[q];
                    v[4*q+0] = t.x; v[4*q+1] = t.y; v[4*q+2] = t.z; v[4*q+3] = t.w;
                }
            }
            float o[24];
            #pragma unroll
            for (int m = 0; m < 8; ++m) {
                float vx = v[3*m+0], vy = v[3*m+1], vz = v[3*m+2];
                o[3*m+0] = fmaf(M0.x, vx, fmaf(M0.y, vy, fmaf(M0.z, vz, M0.w)));
                o[3*m+1] = fmaf(M1.x, vx, fmaf(M1.y, vy, fmaf(M1.z, vz, M1.w)));
                o[3*m+2] = fmaf(M2.x, vx, fmaf(M2.y, vy, fmaf(M2.z, vz, M2.w)));
            }
            union { uint u[12]; uint4 q4[3]; } pk;
            #pragma unroll
            for (int q = 0; q < 12; ++q)
                pk.u[q] = f2bf2(o[2*q], o[2*q+1]);
            uint4* dst = reinterpret_cast<uint4*>(xrow + 48 + pt * 24);
            dst[0] = pk.q4[0]; dst[1] = pk.q4[1]; dst[2] = pk.q4[2];
        }

        // ===== layer 1: acc init = b1 (laundered LDS), then W1-frag x x-frag =====
        f32x4 acc[6][2];
        #pragma unroll
        for (int mt = 0; mt < 6; ++mt) {
            f32x4 bv = *reinterpret_cast<const f32x4*>(bp + mt*16 + rg);
            acc[mt][0] = bv;
            acc[mt][1] = bv;
        }
        bf16x8 xf[2][3];
        #pragma unroll
        for (int nt = 0; nt < 2; ++nt)
            #pragma unroll
            for (int kb = 0; kb < 3; ++kb)
                xf[nt][kb] = *reinterpret_cast<const bf16x8*>(
                    xs + (w*32 + nt*16 + cl) * LDX + kb*32 + g*8);
        #pragma unroll
        for (int mt = 0; mt < 6; ++mt) {
            bf16x8 wfr[3];
            #pragma unroll
            for (int kb = 0; kb < 3; ++kb)
                wfr[kb] = *reinterpret_cast<const bf16x8*>(
                    wp + ((0*18 + mt*3 + kb) * 64 + l) * 8);
            #pragma unroll
            for (int nt = 0; nt < 2; ++nt)
                #pragma unroll
                for (int kb = 0; kb < 3; ++kb)
                    acc[mt][nt] = __builtin_amdgcn_mfma_f32_16x16x32_bf16(
                        wfr[kb], xf[nt][kb], acc[mt][nt], 0, 0, 0);
        }

        // epilogue 1: relu -> packed bf16, b64 write (bias already in acc)
        #pragma unroll
        for (int mt = 0; mt < 6; ++mt) {
            #pragma unroll
            for (int nt = 0; nt < 2; ++nt) {
                uint2 u2;
                u2.x = f2bf2(fmaxf(acc[mt][nt][0], 0.f), fmaxf(acc[mt][nt][1], 0.f));
                u2.y = f2bf2(fmaxf(acc[mt][nt][2], 0.f), fmaxf(acc[mt][nt][3], 0.f));
                *reinterpret_cast<uint2*>(
                    xs + (w*32 + nt*16 + cl) * LDX + mt*16 + rg) = u2;
            }
        }

        // ===== layer 2: acc2 init = b2 =====
        f32x4 acc2[6][2];
        #pragma unroll
        for (int mt = 0; mt < 6; ++mt) {
            f32x4 bv = *reinterpret_cast<const f32x4*>(bp + 96 + mt*16 + rg);
            acc2[mt][0] = bv;
            acc2[mt][1] = bv;
        }
        bf16x8 hf[2][3];
        #pragma unroll
        for (int nt = 0; nt < 2; ++nt)
            #pragma unroll
            for (int kb = 0; kb < 3; ++kb)
                hf[nt][kb] = *reinterpret_cast<const bf16x8*>(
                    xs + (w*32 + nt*16 + cl) * LDX + kb*32 + g*8);
        #pragma unroll
        for (int mt = 0; mt < 6; ++mt) {
            bf16x8 wfr[3];
            #pragma unroll
            for (int kb = 0; kb < 3; ++kb)
                wfr[kb] = *reinterpret_cast<const bf16x8*>(
                    wp + ((1*18 + mt*3 + kb) * 64 + l) * 8);
            #pragma unroll
            for (int nt = 0; nt < 2; ++nt)
                #pragma unroll
                for (int kb = 0; kb < 3; ++kb)
                    acc2[mt][nt] = __builtin_amdgcn_mfma_f32_16x16x32_bf16(
                        wfr[kb], hf[nt][kb], acc2[mt][nt], 0, 0, 0);
        }

        // epilogue 2: relu + W3 dot (laundered LDS), 2 shuffles, coalesced store
        float pr0 = 0.f, pr1 = 0.f;
        #pragma unroll
        for (int mt = 0; mt < 6; ++mt) {
            f32x4 w3v = *reinterpret_cast<const f32x4*>(bp + 192 + mt*16 + rg);
            pr0 = fmaf(fmaxf(acc2[mt][0][0], 0.f), w3v[0], pr0);
            pr0 = fmaf(fmaxf(acc2[mt][0][1], 0.f), w3v[1], pr0);
            pr0 = fmaf(fmaxf(acc2[mt][0][2], 0.f), w3v[2], pr0);
            pr0 = fmaf(fmaxf(acc2[mt][0][3], 0.f), w3v[3], pr0);
            pr1 = fmaf(fmaxf(acc2[mt][1][0], 0.f), w3v[0], pr1);
            pr1 = fmaf(fmaxf(acc2[mt][1][1], 0.f), w3v[1], pr1);
            pr1 = fmaf(fmaxf(acc2[mt][1][2], 0.f), w3v[2], pr1);
            pr1 = fmaf(fmaxf(acc2[mt][1][3], 0.f), w3v[3], pr1);
        }
        pr0 += __shfl_xor(pr0, 16, 64);
        pr0 += __shfl_xor(pr0, 32, 64);
        pr1 += __shfl_xor(pr1, 16, 64);
        pr1 += __shfl_xor(pr1, 32, 64);
        if (l < 16)
            out[pbase + l] = 0.5f * (pr0 + pr1) + bp[288];
    }
}

extern "C" void kernel_launch(void* const* d_in, const int* in_sizes, int n_in,
                              void* d_out, int out_size, void* d_ws, size_t ws_size,
                              hipStream_t stream) {
    const int*   o1    = (const int*)d_in[0];
    const int*   o2    = (const int*)d_in[1];
    const float* T     = (const float*)d_in[2];
    const float* geoms = (const float*)d_in[3];
    const float* W1    = (const float*)d_in[4];
    const float* b1    = (const float*)d_in[5];
    const float* W2    = (const float*)d_in[6];
    const float* b2    = (const float*)d_in[7];
    const float* W3    = (const float*)d_in[8];
    const float* b3    = (const float*)d_in[9];
    float* out = (float*)d_out;
    const int N  = in_sizes[0];
    const int NG = in_sizes[3];           // 48000

    ushort* gbf = (ushort*)d_ws;
    uint*   cnt = (uint*)((char*)d_ws + CNT_OFF);

    hipLaunchKernelGGL(prep_geoms, dim3((NG + 255) / 256), dim3(256), 0, stream,
                       geoms, gbf, cnt, NG);
    hipLaunchKernelGGL(collision_mfma, dim3(NBLK), dim3(BT), 0, stream,
                       o1, o2, T, geoms, gbf, cnt, W1, b1, W2, b2, W3, b3, out, N);
}

// Round 20
// 132.749 us; speedup vs baseline: 5.8279x; 5.8279x over previous
//
#include <hip/hip_runtime.h>
#include <hip/hip_bf16.h>

typedef __attribute__((ext_vector_type(8))) short bf16x8;
typedef __attribute__((ext_vector_type(4))) float f32x4;

constexpr int BT   = 1024;  // threads/block (16 waves, 1 block/CU)
constexpr int KD   = 96;    // feature/hidden dim
constexpr int LDX  = 104;   // xs row stride in bf16 (208 B, 16B-aligned)
constexpr int LDT  = 12;    // tinv stride in floats (48 B)
constexpr int NBLK = 256;   // persistent blocks (1 per CU)
constexpr int TOTW = NBLK * (BT / 64);   // 4096 wave slots

__device__ inline ushort f2bf(float f) {  // fp32 -> bf16 RNE
    uint u = __float_as_uint(f);
    u += 0x7fffu + ((u >> 16) & 1u);
    return (ushort)(u >> 16);
}

__device__ inline uint f2bf2(float lo, float hi) {  // packed cvt
    float2 t; t.x = lo; t.y = hi;
    __hip_bfloat162 h = __float22bfloat162_rn(t);
    union { __hip_bfloat162 b; uint u; } cv;
    cv.b = h;
    return cv.u;
}

// prep: geoms f32 -> bf16 table in d_ws
__global__ void prep_geoms(const float* __restrict__ g, ushort* __restrict__ gb, int n) {
    int i = blockIdx.x * 256 + threadIdx.x;
    if (i < n) gb[i] = f2bf(g[i]);
}

// f64 adjugate 4x4 inverse; writes rows 0..2 (3x4 floats) to ti
__device__ inline void inv4x4(float4 t0, float4 t1, float4 t2, float4 t3,
                              float* __restrict__ ti) {
    double m00=t0.x, m01=t0.y, m02=t0.z, m03=t0.w;
    double m10=t1.x, m11=t1.y, m12=t1.z, m13=t1.w;
    double m20=t2.x, m21=t2.y, m22=t2.z, m23=t2.w;
    double m30=t3.x, m31=t3.y, m32=t3.z, m33=t3.w;
    double A2323 = m22*m33 - m23*m32;
    double A1323 = m21*m33 - m23*m31;
    double A1223 = m21*m32 - m22*m31;
    double A0323 = m20*m33 - m23*m30;
    double A0223 = m20*m32 - m22*m30;
    double A0123 = m20*m31 - m21*m30;
    double A2313 = m12*m33 - m13*m32;
    double A1313 = m11*m33 - m13*m31;
    double A1213 = m11*m32 - m12*m31;
    double A2312 = m12*m23 - m13*m22;
    double A1312 = m11*m23 - m13*m21;
    double A1212 = m11*m22 - m12*m21;
    double A0313 = m10*m33 - m13*m30;
    double A0213 = m10*m32 - m12*m30;
    double A0312 = m10*m23 - m13*m20;
    double A0212 = m10*m22 - m12*m20;
    double A0113 = m10*m31 - m11*m30;
    double A0112 = m10*m21 - m11*m20;
    double det = m00*(m11*A2323 - m12*A1323 + m13*A1223)
               - m01*(m10*A2323 - m12*A0323 + m13*A0223)
               + m02*(m10*A1323 - m11*A0323 + m13*A0123)
               - m03*(m10*A1223 - m11*A0223 + m12*A0123);
    double idet = 1.0 / det;
    ti[0]  = (float)( idet *  (m11*A2323 - m12*A1323 + m13*A1223) );
    ti[1]  = (float)( idet * -(m01*A2323 - m02*A1323 + m03*A1223) );
    ti[2]  = (float)( idet *  (m01*A2313 - m02*A1313 + m03*A1213) );
    ti[3]  = (float)( idet * -(m01*A2312 - m02*A1312 + m03*A1212) );
    ti[4]  = (float)( idet * -(m10*A2323 - m12*A0323 + m13*A0223) );
    ti[5]  = (float)( idet *  (m00*A2323 - m02*A0323 + m03*A0223) );
    ti[6]  = (float)( idet * -(m00*A2313 - m02*A0313 + m03*A0213) );
    ti[7]  = (float)( idet *  (m00*A2312 - m02*A0312 + m03*A0212) );
    ti[8]  = (float)( idet *  (m10*A1323 - m11*A0323 + m13*A0123) );
    ti[9]  = (float)( idet * -(m00*A1323 - m01*A0323 + m03*A0123) );
    ti[10] = (float)( idet *  (m00*A1313 - m01*A0313 + m03*A0113) );
    ti[11] = (float)( idet * -(m00*A1312 - m01*A0312 + m03*A0112) );
}

__global__ void __launch_bounds__(BT, 4) collision_mfma(
    const int* __restrict__ o1, const int* __restrict__ o2,
    const float* __restrict__ Tg, const float* __restrict__ geoms,
    const ushort* __restrict__ gbf,
    const float* __restrict__ W1, const float* __restrict__ b1,
    const float* __restrict__ W2, const float* __restrict__ b2,
    const float* __restrict__ W3, const float* __restrict__ b3,
    float* __restrict__ out, int N)
{
    __shared__ ushort xs[512 * LDX];      // 16 waves x 32 rows (106496 B)
    __shared__ ushort wlds[36 * 64 * 8];  // frag-major weights (36864 B)
    __shared__ float  tinv[256 * LDT];    // 16 waves x 16 pairs (12288 B)
    __shared__ float  bls[292];           // b1 | b2 | W3 | b3 (1168 B)

    const int tid = threadIdx.x;
    const int w   = tid >> 6;      // wave 0..15
    const int l   = tid & 63;      // lane
    const int cl  = l & 15;        // fragment col within 16-tile
    const int g   = l >> 4;        // k-group 0..3
    const int rg  = g * 4;

    // staging roles (fixed per lane)
    const int rl = l & 31;         // local row 0..31
    const int pt = l >> 5;         // part: elems [pt*24, pt*24+24)
    const int br = rl >> 4;        // branch 0: (x1, T x2)  1: (x2, Tinv x1)
    const int dp = rl & 15;        // local pair 0..15

    // ---- stage weights frag-major + bias/W3, once ----
    for (int e = tid; e < 36 * 512; e += BT) {
        int f    = e >> 9;
        int r    = e & 511;
        int lane = r >> 3;
        int j    = r & 7;
        int L    = f / 18;
        int fr   = f - L * 18;
        int mt   = fr / 3;
        int kb   = fr - mt * 3;
        int gg   = lane >> 4;
        int cc   = lane & 15;
        const float* W = L ? W2 : W1;
        wlds[e] = f2bf(W[(kb * 32 + gg * 8 + j) * KD + mt * 16 + cc]);
    }
    if (tid < 96) {
        bls[tid]       = b1[tid];
        bls[96 + tid]  = b2[tid];
        bls[192 + tid] = W3[tid];
    }
    if (tid == 96) bls[288] = b3[0];
    __syncthreads();   // only runtime barrier; main loop is wave-private

    const int NWT = N >> 4;
    const int gw  = blockIdx.x * (BT / 64) + w;

    for (int wt = gw; wt < NWT; wt += TOTW) {
        const int pbase = wt * 16;

        // surgical anti-LICM: opaque zero offset, re-made each iteration.
        // wlds/bls reads through wp/bp can't be hoisted (r3/r4/r14 spill guard);
        // everything else schedules freely (no memory clobber).
        uint off0 = 0;
        asm volatile("" : "+v"(off0));
        const ushort* wp = wlds + off0;
        const float*  bp = bls + off0;

        // ===== phase 1: f64 4x4 inverse, lanes 0..15 (wave-private tinv) =====
        if (l < 16) {
            const float4* T4 = reinterpret_cast<const float4*>(Tg + (size_t)(pbase + l) * 16);
            float4 t0 = T4[0], t1 = T4[1], t2 = T4[2], t3 = T4[3];
            inv4x4(t0, t1, t2, t3, &tinv[(w * 16 + l) * LDT]);
        }

        // ===== phase 2: staging, lane = half-row =====
        {
            const int p  = pbase + dp;
            const int ia = o1[p], ib = o2[p];
            const int oa = br ? ib : ia;
            const int ob = br ? ia : ib;
            ushort* xrow = xs + (w * 32 + rl) * LDX;

            // copy half (24 bf16 from pre-converted table)
            {
                const uint4* src = reinterpret_cast<const uint4*>(gbf + oa * 48 + pt * 24);
                uint4* dst = reinterpret_cast<uint4*>(xrow + pt * 24);
                dst[0] = src[0]; dst[1] = src[1]; dst[2] = src[2];
            }

            // transform half: 8 vec3s
            float4 M0, M1, M2;
            if (br == 0) {
                const float4* Tp = reinterpret_cast<const float4*>(Tg + (size_t)p * 16);
                M0 = Tp[0]; M1 = Tp[1]; M2 = Tp[2];
            } else {
                const float4* t4 = reinterpret_cast<const float4*>(&tinv[(w * 16 + dp) * LDT]);
                M0 = t4[0]; M1 = t4[1]; M2 = t4[2];
            }
            float v[24];
            {
                const float4* bs = reinterpret_cast<const float4*>(geoms + (size_t)ob * 48 + pt * 24);
                #pragma unroll
                for (int q = 0; q < 6; ++q) {
                    float4 t = bs[q];
                    v[4*q+0] = t.x; v[4*q+1] = t.y; v[4*q+2] = t.z; v[4*q+3] = t.w;
                }
            }
            float o[24];
            #pragma unroll
            for (int m = 0; m < 8; ++m) {
                float vx = v[3*m+0], vy = v[3*m+1], vz = v[3*m+2];
                o[3*m+0] = fmaf(M0.x, vx, fmaf(M0.y, vy, fmaf(M0.z, vz, M0.w)));
                o[3*m+1] = fmaf(M1.x, vx, fmaf(M1.y, vy, fmaf(M1.z, vz, M1.w)));
                o[3*m+2] = fmaf(M2.x, vx, fmaf(M2.y, vy, fmaf(M2.z, vz, M2.w)));
            }
            union { uint u[12]; uint4 q4[3]; } pk;
            #pragma unroll
            for (int q = 0; q < 12; ++q)
                pk.u[q] = f2bf2(o[2*q], o[2*q+1]);
            uint4* dst = reinterpret_cast<uint4*>(xrow + 48 + pt * 24);
            dst[0] = pk.q4[0]; dst[1] = pk.q4[1]; dst[2] = pk.q4[2];
        }

        // ===== layer 1: acc init = b1 (laundered LDS), then W1-frag x x-frag =====
        f32x4 acc[6][2];
        #pragma unroll
        for (int mt = 0; mt < 6; ++mt) {
            f32x4 bv = *reinterpret_cast<const f32x4*>(bp + mt*16 + rg);
            acc[mt][0] = bv;
            acc[mt][1] = bv;
        }
        bf16x8 xf[2][3];
        #pragma unroll
        for (int nt = 0; nt < 2; ++nt)
            #pragma unroll
            for (int kb = 0; kb < 3; ++kb)
                xf[nt][kb] = *reinterpret_cast<const bf16x8*>(
                    xs + (w*32 + nt*16 + cl) * LDX + kb*32 + g*8);
        #pragma unroll
        for (int mt = 0; mt < 6; ++mt) {
            bf16x8 wfr[3];
            #pragma unroll
            for (int kb = 0; kb < 3; ++kb)
                wfr[kb] = *reinterpret_cast<const bf16x8*>(
                    wp + ((0*18 + mt*3 + kb) * 64 + l) * 8);
            #pragma unroll
            for (int nt = 0; nt < 2; ++nt)
                #pragma unroll
                for (int kb = 0; kb < 3; ++kb)
                    acc[mt][nt] = __builtin_amdgcn_mfma_f32_16x16x32_bf16(
                        wfr[kb], xf[nt][kb], acc[mt][nt], 0, 0, 0);
        }

        // epilogue 1: relu -> packed bf16, b64 write (bias already in acc)
        #pragma unroll
        for (int mt = 0; mt < 6; ++mt) {
            #pragma unroll
            for (int nt = 0; nt < 2; ++nt) {
                uint2 u2;
                u2.x = f2bf2(fmaxf(acc[mt][nt][0], 0.f), fmaxf(acc[mt][nt][1], 0.f));
                u2.y = f2bf2(fmaxf(acc[mt][nt][2], 0.f), fmaxf(acc[mt][nt][3], 0.f));
                *reinterpret_cast<uint2*>(
                    xs + (w*32 + nt*16 + cl) * LDX + mt*16 + rg) = u2;
            }
        }

        // ===== layer 2: acc2 init = b2 =====
        f32x4 acc2[6][2];
        #pragma unroll
        for (int mt = 0; mt < 6; ++mt) {
            f32x4 bv = *reinterpret_cast<const f32x4*>(bp + 96 + mt*16 + rg);
            acc2[mt][0] = bv;
            acc2[mt][1] = bv;
        }
        bf16x8 hf[2][3];
        #pragma unroll
        for (int nt = 0; nt < 2; ++nt)
            #pragma unroll
            for (int kb = 0; kb < 3; ++kb)
                hf[nt][kb] = *reinterpret_cast<const bf16x8*>(
                    xs + (w*32 + nt*16 + cl) * LDX + kb*32 + g*8);
        #pragma unroll
        for (int mt = 0; mt < 6; ++mt) {
            bf16x8 wfr[3];
            #pragma unroll
            for (int kb = 0; kb < 3; ++kb)
                wfr[kb] = *reinterpret_cast<const bf16x8*>(
                    wp + ((1*18 + mt*3 + kb) * 64 + l) * 8);
            #pragma unroll
            for (int nt = 0; nt < 2; ++nt)
                #pragma unroll
                for (int kb = 0; kb < 3; ++kb)
                    acc2[mt][nt] = __builtin_amdgcn_mfma_f32_16x16x32_bf16(
                        wfr[kb], hf[nt][kb], acc2[mt][nt], 0, 0, 0);
        }

        // epilogue 2: relu + W3 dot (laundered LDS), 2 shuffles, coalesced store
        float pr0 = 0.f, pr1 = 0.f;
        #pragma unroll
        for (int mt = 0; mt < 6; ++mt) {
            f32x4 w3v = *reinterpret_cast<const f32x4*>(bp + 192 + mt*16 + rg);
            pr0 = fmaf(fmaxf(acc2[mt][0][0], 0.f), w3v[0], pr0);
            pr0 = fmaf(fmaxf(acc2[mt][0][1], 0.f), w3v[1], pr0);
            pr0 = fmaf(fmaxf(acc2[mt][0][2], 0.f), w3v[2], pr0);
            pr0 = fmaf(fmaxf(acc2[mt][0][3], 0.f), w3v[3], pr0);
            pr1 = fmaf(fmaxf(acc2[mt][1][0], 0.f), w3v[0], pr1);
            pr1 = fmaf(fmaxf(acc2[mt][1][1], 0.f), w3v[1], pr1);
            pr1 = fmaf(fmaxf(acc2[mt][1][2], 0.f), w3v[2], pr1);
            pr1 = fmaf(fmaxf(acc2[mt][1][3], 0.f), w3v[3], pr1);
        }
        pr0 += __shfl_xor(pr0, 16, 64);
        pr0 += __shfl_xor(pr0, 32, 64);
        pr1 += __shfl_xor(pr1, 16, 64);
        pr1 += __shfl_xor(pr1, 32, 64);
        if (l < 16)
            out[pbase + l] = 0.5f * (pr0 + pr1) + bp[288];
    }
}

extern "C" void kernel_launch(void* const* d_in, const int* in_sizes, int n_in,
                              void* d_out, int out_size, void* d_ws, size_t ws_size,
                              hipStream_t stream) {
    const int*   o1    = (const int*)d_in[0];
    const int*   o2    = (const int*)d_in[1];
    const float* T     = (const float*)d_in[2];
    const float* geoms = (const float*)d_in[3];
    const float* W1    = (const float*)d_in[4];
    const float* b1    = (const float*)d_in[5];
    const float* W2    = (const float*)d_in[6];
    const float* b2    = (const float*)d_in[7];
    const float* W3    = (const float*)d_in[8];
    const float* b3    = (const float*)d_in[9];
    float* out = (float*)d_out;
    const int N  = in_sizes[0];
    const int NG = in_sizes[3];           // 48000

    ushort* gbf = (ushort*)d_ws;
    hipLaunchKernelGGL(prep_geoms, dim3((NG + 255) / 256), dim3(256), 0, stream,
                       geoms, gbf, NG);
    hipLaunchKernelGGL(collision_mfma, dim3(NBLK), dim3(BT), 0, stream,
                       o1, o2, T, geoms, gbf, W1, b1, W2, b2, W3, b3, out, N);
}

// Round 21
// 129.976 us; speedup vs baseline: 5.9522x; 1.0213x over previous
//
#include <hip/hip_runtime.h>
#include <hip/hip_bf16.h>

typedef __attribute__((ext_vector_type(8))) short bf16x8;
typedef __attribute__((ext_vector_type(4))) float f32x4;

constexpr int BT   = 1024;  // threads/block (16 waves, 1 block/CU)
constexpr int KD   = 96;    // feature/hidden dim
constexpr int LDX  = 104;   // xs row stride in bf16 (208 B, 16B-aligned)
constexpr int NBLK = 256;   // persistent blocks (1 per CU)
constexpr int TOTW = NBLK * (BT / 64);   // 4096 wave slots

__device__ inline ushort f2bf(float f) {  // fp32 -> bf16 RNE
    uint u = __float_as_uint(f);
    u += 0x7fffu + ((u >> 16) & 1u);
    return (ushort)(u >> 16);
}

__device__ inline uint f2bf2(float lo, float hi) {  // packed cvt
    float2 t; t.x = lo; t.y = hi;
    __hip_bfloat162 h = __float22bfloat162_rn(t);
    union { __hip_bfloat162 b; uint u; } cv;
    cv.b = h;
    return cv.u;
}

// prep: geoms f32 -> bf16 table in d_ws
__global__ void prep_geoms(const float* __restrict__ g, ushort* __restrict__ gb, int n) {
    int i = blockIdx.x * 256 + threadIdx.x;
    if (i < n) gb[i] = f2bf(g[i]);
}

// f64 adjugate 4x4 inverse; writes rows 0..2 (3x4 floats) to ti (const idx -> SROA)
__device__ inline void inv4x4(float4 t0, float4 t1, float4 t2, float4 t3,
                              float* __restrict__ ti) {
    double m00=t0.x, m01=t0.y, m02=t0.z, m03=t0.w;
    double m10=t1.x, m11=t1.y, m12=t1.z, m13=t1.w;
    double m20=t2.x, m21=t2.y, m22=t2.z, m23=t2.w;
    double m30=t3.x, m31=t3.y, m32=t3.z, m33=t3.w;
    double A2323 = m22*m33 - m23*m32;
    double A1323 = m21*m33 - m23*m31;
    double A1223 = m21*m32 - m22*m31;
    double A0323 = m20*m33 - m23*m30;
    double A0223 = m20*m32 - m22*m30;
    double A0123 = m20*m31 - m21*m30;
    double A2313 = m12*m33 - m13*m32;
    double A1313 = m11*m33 - m13*m31;
    double A1213 = m11*m32 - m12*m31;
    double A2312 = m12*m23 - m13*m22;
    double A1312 = m11*m23 - m13*m21;
    double A1212 = m11*m22 - m12*m21;
    double A0313 = m10*m33 - m13*m30;
    double A0213 = m10*m32 - m12*m30;
    double A0312 = m10*m23 - m13*m20;
    double A0212 = m10*m22 - m12*m20;
    double A0113 = m10*m31 - m11*m30;
    double A0112 = m10*m21 - m11*m20;
    double det = m00*(m11*A2323 - m12*A1323 + m13*A1223)
               - m01*(m10*A2323 - m12*A0323 + m13*A0223)
               + m02*(m10*A1323 - m11*A0323 + m13*A0123)
               - m03*(m10*A1223 - m11*A0223 + m12*A0123);
    double idet = 1.0 / det;
    ti[0]  = (float)( idet *  (m11*A2323 - m12*A1323 + m13*A1223) );
    ti[1]  = (float)( idet * -(m01*A2323 - m02*A1323 + m03*A1223) );
    ti[2]  = (float)( idet *  (m01*A2313 - m02*A1313 + m03*A1213) );
    ti[3]  = (float)( idet * -(m01*A2312 - m02*A1312 + m03*A1212) );
    ti[4]  = (float)( idet * -(m10*A2323 - m12*A0323 + m13*A0223) );
    ti[5]  = (float)( idet *  (m00*A2323 - m02*A0323 + m03*A0223) );
    ti[6]  = (float)( idet * -(m00*A2313 - m02*A0313 + m03*A0213) );
    ti[7]  = (float)( idet *  (m00*A2312 - m02*A0312 + m03*A0212) );
    ti[8]  = (float)( idet *  (m10*A1323 - m11*A0323 + m13*A0123) );
    ti[9]  = (float)( idet * -(m00*A1323 - m01*A0323 + m03*A0123) );
    ti[10] = (float)( idet *  (m00*A1313 - m01*A0313 + m03*A0113) );
    ti[11] = (float)( idet * -(m00*A1312 - m01*A0312 + m03*A0112) );
}

__global__ void __launch_bounds__(BT, 4) collision_mfma(
    const int* __restrict__ o1, const int* __restrict__ o2,
    const float* __restrict__ Tg, const float* __restrict__ geoms,
    const ushort* __restrict__ gbf,
    const float* __restrict__ W1, const float* __restrict__ b1,
    const float* __restrict__ W2, const float* __restrict__ b2,
    const float* __restrict__ W3, const float* __restrict__ b3,
    float* __restrict__ out, int N)
{
    __shared__ ushort xs[512 * LDX];      // 16 waves x 32 rows (106496 B)
    __shared__ ushort wlds[36 * 64 * 8];  // frag-major weights (36864 B)
    __shared__ float  bls[292];           // b1 | b2 | W3 | b3 (1168 B)

    const int tid = threadIdx.x;
    const int w   = tid >> 6;      // wave 0..15
    const int l   = tid & 63;      // lane
    const int cl  = l & 15;        // fragment col within 16-tile
    const int g   = l >> 4;        // k-group 0..3
    const int rg  = g * 4;

    // staging roles (fixed per lane)
    const int rl = l & 31;         // local row 0..31
    const int pt = l >> 5;         // part: elems [pt*24, pt*24+24)
    const int br = rl >> 4;        // branch 0: (x1, T x2)  1: (x2, Tinv x1)
    const int dp = rl & 15;        // local pair 0..15

    // ---- stage weights frag-major + bias/W3, once ----
    for (int e = tid; e < 36 * 512; e += BT) {
        int f    = e >> 9;
        int r    = e & 511;
        int lane = r >> 3;
        int j    = r & 7;
        int L    = f / 18;
        int fr   = f - L * 18;
        int mt   = fr / 3;
        int kb   = fr - mt * 3;
        int gg   = lane >> 4;
        int cc   = lane & 15;
        const float* W = L ? W2 : W1;
        wlds[e] = f2bf(W[(kb * 32 + gg * 8 + j) * KD + mt * 16 + cc]);
    }
    if (tid < 96) {
        bls[tid]       = b1[tid];
        bls[96 + tid]  = b2[tid];
        bls[192 + tid] = W3[tid];
    }
    if (tid == 96) bls[288] = b3[0];
    __syncthreads();   // only runtime barrier; main loop is wave-private

    const int NWT = N >> 4;
    const int gw  = blockIdx.x * (BT / 64) + w;

    for (int wt = gw; wt < NWT; wt += TOTW) {
        const int pbase = wt * 16;

        // surgical anti-LICM: opaque zero offset, re-made each iteration.
        // wlds/bls reads through wp/bp can't be hoisted (r3/r4/r14 spill guard);
        // everything else schedules freely (no memory clobber).
        uint off0 = 0;
        asm volatile("" : "+v"(off0));
        const ushort* wp = wlds + off0;
        const float*  bp = bls + off0;

        // ===== phase 1+2 fused: per-lane inverse (all 64 lanes — exec-masked
        // version costs IDENTICAL issue cycles, so redundancy is free) + staging.
        // Removes the tinv LDS round trip from the critical path entirely.
        {
            const int p  = pbase + dp;
            const int ia = o1[p], ib = o2[p];
            const int oa = br ? ib : ia;
            const int ob = br ? ia : ib;
            ushort* xrow = xs + (w * 32 + rl) * LDX;

            // this lane's pair T (also the br=0 transform matrix rows 0..2)
            const float4* T4 = reinterpret_cast<const float4*>(Tg + (size_t)p * 16);
            float4 t0 = T4[0], t1 = T4[1], t2 = T4[2], t3 = T4[3];

            // copy half (24 bf16 from pre-converted table)
            {
                const uint4* src = reinterpret_cast<const uint4*>(gbf + oa * 48 + pt * 24);
                uint4* dst = reinterpret_cast<uint4*>(xrow + pt * 24);
                dst[0] = src[0]; dst[1] = src[1]; dst[2] = src[2];
            }

            // in-register inverse (every lane, its own pair; no LDS, no guard)
            float ti[12];
            inv4x4(t0, t1, t2, t3, ti);

            float4 M0, M1, M2;
            if (br == 0) {
                M0 = t0; M1 = t1; M2 = t2;
            } else {
                M0 = make_float4(ti[0], ti[1], ti[2],  ti[3]);
                M1 = make_float4(ti[4], ti[5], ti[6],  ti[7]);
                M2 = make_float4(ti[8], ti[9], ti[10], ti[11]);
            }

            float v[24];
            {
                const float4* bs = reinterpret_cast<const float4*>(geoms + (size_t)ob * 48 + pt * 24);
                #pragma unroll
                for (int q = 0; q < 6; ++q) {
                    float4 t = bs[q];
                    v[4*q+0] = t.x; v[4*q+1] = t.y; v[4*q+2] = t.z; v[4*q+3] = t.w;
                }
            }
            float o[24];
            #pragma unroll
            for (int m = 0; m < 8; ++m) {
                float vx = v[3*m+0], vy = v[3*m+1], vz = v[3*m+2];
                o[3*m+0] = fmaf(M0.x, vx, fmaf(M0.y, vy, fmaf(M0.z, vz, M0.w)));
                o[3*m+1] = fmaf(M1.x, vx, fmaf(M1.y, vy, fmaf(M1.z, vz, M1.w)));
                o[3*m+2] = fmaf(M2.x, vx, fmaf(M2.y, vy, fmaf(M2.z, vz, M2.w)));
            }
            union { uint u[12]; uint4 q4[3]; } pk;
            #pragma unroll
            for (int q = 0; q < 12; ++q)
                pk.u[q] = f2bf2(o[2*q], o[2*q+1]);
            uint4* dst = reinterpret_cast<uint4*>(xrow + 48 + pt * 24);
            dst[0] = pk.q4[0]; dst[1] = pk.q4[1]; dst[2] = pk.q4[2];
        }

        // ===== layer 1: acc init = b1 (laundered LDS), then W1-frag x x-frag =====
        f32x4 acc[6][2];
        #pragma unroll
        for (int mt = 0; mt < 6; ++mt) {
            f32x4 bv = *reinterpret_cast<const f32x4*>(bp + mt*16 + rg);
            acc[mt][0] = bv;
            acc[mt][1] = bv;
        }
        bf16x8 xf[2][3];
        #pragma unroll
        for (int nt = 0; nt < 2; ++nt)
            #pragma unroll
            for (int kb = 0; kb < 3; ++kb)
                xf[nt][kb] = *reinterpret_cast<const bf16x8*>(
                    xs + (w*32 + nt*16 + cl) * LDX + kb*32 + g*8);
        #pragma unroll
        for (int mt = 0; mt < 6; ++mt) {
            bf16x8 wfr[3];
            #pragma unroll
            for (int kb = 0; kb < 3; ++kb)
                wfr[kb] = *reinterpret_cast<const bf16x8*>(
                    wp + ((0*18 + mt*3 + kb) * 64 + l) * 8);
            #pragma unroll
            for (int nt = 0; nt < 2; ++nt)
                #pragma unroll
                for (int kb = 0; kb < 3; ++kb)
                    acc[mt][nt] = __builtin_amdgcn_mfma_f32_16x16x32_bf16(
                        wfr[kb], xf[nt][kb], acc[mt][nt], 0, 0, 0);
        }

        // epilogue 1: relu -> packed bf16, b64 write (bias already in acc)
        #pragma unroll
        for (int mt = 0; mt < 6; ++mt) {
            #pragma unroll
            for (int nt = 0; nt < 2; ++nt) {
                uint2 u2;
                u2.x = f2bf2(fmaxf(acc[mt][nt][0], 0.f), fmaxf(acc[mt][nt][1], 0.f));
                u2.y = f2bf2(fmaxf(acc[mt][nt][2], 0.f), fmaxf(acc[mt][nt][3], 0.f));
                *reinterpret_cast<uint2*>(
                    xs + (w*32 + nt*16 + cl) * LDX + mt*16 + rg) = u2;
            }
        }

        // ===== layer 2: acc2 init = b2 =====
        f32x4 acc2[6][2];
        #pragma unroll
        for (int mt = 0; mt < 6; ++mt) {
            f32x4 bv = *reinterpret_cast<const f32x4*>(bp + 96 + mt*16 + rg);
            acc2[mt][0] = bv;
            acc2[mt][1] = bv;
        }
        bf16x8 hf[2][3];
        #pragma unroll
        for (int nt = 0; nt < 2; ++nt)
            #pragma unroll
            for (int kb = 0; kb < 3; ++kb)
                hf[nt][kb] = *reinterpret_cast<const bf16x8*>(
                    xs + (w*32 + nt*16 + cl) * LDX + kb*32 + g*8);
        #pragma unroll
        for (int mt = 0; mt < 6; ++mt) {
            bf16x8 wfr[3];
            #pragma unroll
            for (int kb = 0; kb < 3; ++kb)
                wfr[kb] = *reinterpret_cast<const bf16x8*>(
                    wp + ((1*18 + mt*3 + kb) * 64 + l) * 8);
            #pragma unroll
            for (int nt = 0; nt < 2; ++nt)
                #pragma unroll
                for (int kb = 0; kb < 3; ++kb)
                    acc2[mt][nt] = __builtin_amdgcn_mfma_f32_16x16x32_bf16(
                        wfr[kb], hf[nt][kb], acc2[mt][nt], 0, 0, 0);
        }

        // epilogue 2: relu + W3 dot (laundered LDS), 2 shuffles, coalesced store
        float pr0 = 0.f, pr1 = 0.f;
        #pragma unroll
        for (int mt = 0; mt < 6; ++mt) {
            f32x4 w3v = *reinterpret_cast<const f32x4*>(bp + 192 + mt*16 + rg);
            pr0 = fmaf(fmaxf(acc2[mt][0][0], 0.f), w3v[0], pr0);
            pr0 = fmaf(fmaxf(acc2[mt][0][1], 0.f), w3v[1], pr0);
            pr0 = fmaf(fmaxf(acc2[mt][0][2], 0.f), w3v[2], pr0);
            pr0 = fmaf(fmaxf(acc2[mt][0][3], 0.f), w3v[3], pr0);
            pr1 = fmaf(fmaxf(acc2[mt][1][0], 0.f), w3v[0], pr1);
            pr1 = fmaf(fmaxf(acc2[mt][1][1], 0.f), w3v[1], pr1);
            pr1 = fmaf(fmaxf(acc2[mt][1][2], 0.f), w3v[2], pr1);
            pr1 = fmaf(fmaxf(acc2[mt][1][3], 0.f), w3v[3], pr1);
        }
        pr0 += __shfl_xor(pr0, 16, 64);
        pr0 += __shfl_xor(pr0, 32, 64);
        pr1 += __shfl_xor(pr1, 16, 64);
        pr1 += __shfl_xor(pr1, 32, 64);
        if (l < 16)
            out[pbase + l] = 0.5f * (pr0 + pr1) + bp[288];
    }
}

extern "C" void kernel_launch(void* const* d_in, const int* in_sizes, int n_in,
                              void* d_out, int out_size, void* d_ws, size_t ws_size,
                              hipStream_t stream) {
    const int*   o1    = (const int*)d_in[0];
    const int*   o2    = (const int*)d_in[1];
    const float* T     = (const float*)d_in[2];
    const float* geoms = (const float*)d_in[3];
    const float* W1    = (const float*)d_in[4];
    const float* b1    = (const float*)d_in[5];
    const float* W2    = (const float*)d_in[6];
    const float* b2    = (const float*)d_in[7];
    const float* W3    = (const float*)d_in[8];
    const float* b3    = (const float*)d_in[9];
    float* out = (float*)d_out;
    const int N  = in_sizes[0];
    const int NG = in_sizes[3];           // 48000

    ushort* gbf = (ushort*)d_ws;
    hipLaunchKernelGGL(prep_geoms, dim3((NG + 255) / 256), dim3(256), 0, stream,
                       geoms, gbf, NG);
    hipLaunchKernelGGL(collision_mfma, dim3(NBLK), dim3(BT), 0, stream,
                       o1, o2, T, geoms, gbf, W1, b1, W2, b2, W3, b3, out, N);
}